// Round 10
// baseline (425.324 us; speedup 1.0000x reference)
//
#include <hip/hip_runtime.h>
#include <hip/hip_cooperative_groups.h>
#include <hip/hip_bf16.h>
#include <math.h>

namespace cg = cooperative_groups;

#define NN 4096      // nodes
#define C  256       // feature dim
#define NH 8         // heads
#define HD 32        // head dim
#define LN_EPS 1e-5f
#define LOG2E 1.44269504088896340736f

typedef unsigned short u16;
typedef __attribute__((ext_vector_type(8))) short bf16x8;
typedef __attribute__((ext_vector_type(4))) float f32x4;

#define TQ 64
#define TJ 64
#define KSTRIDE 40   // Ks row stride (bf16)
#define VSTRIDE 72   // Vs/Ps row stride (bf16)
#define TRS 80       // qkv LDS transpose row stride (u16)
#define OROWS 8
#define ZERO_FLOATS ((size_t)NN * C + (size_t)NN * NH)

__device__ inline u16 f2b(float f) {
    union { float f; unsigned u; } v; v.f = f;
    unsigned r = (v.u + 0x7fff + ((v.u >> 16) & 1)) >> 16;  // RNE
    return (u16)r;
}

__device__ inline float fexp2(float x) {
#if __has_builtin(__builtin_amdgcn_exp2f)
    return __builtin_amdgcn_exp2f(x);      // single v_exp_f32
#else
    return exp2f(x);
#endif
}

// pack bf16(e0) | bf16(e1)<<16 by truncation: ONE v_perm_b32
__device__ inline unsigned pack_trunc(float e0, float e1) {
    return __builtin_amdgcn_perm(__float_as_uint(e1), __float_as_uint(e0),
                                 0x07060302u);
}

__device__ inline void atomic_add_agent(float* p, float v) {
    __hip_atomic_fetch_add(p, v, __ATOMIC_RELAXED, __HIP_MEMORY_SCOPE_AGENT);
}

struct SMemAttn {
    u16 Ks[TJ * KSTRIDE];
    u16 Vs[HD * VSTRIDE];
    u16 Ps[4][16 * VSTRIDE];
};
union SMem {                       // max = attn: 18944 B
    SMemAttn a;
    float tile[32][33];
    u16 tr[64 * TRS];
    float sums[2][4][OROWS];
};

// ---------------------------------------------------------------------------
// ONE cooperative kernel: prep+zero -> qkv -> attn -> out_ln, grid.sync()
// between phases. All phases are grid-size-agnostic job loops.
// ---------------------------------------------------------------------------
__global__ __launch_bounds__(256, 6) void fused_kernel(
    const float* __restrict__ x,
    const float* __restrict__ Wq, const float* __restrict__ bq,
    const float* __restrict__ Wk, const float* __restrict__ bk,
    const float* __restrict__ Wv, const float* __restrict__ bv,
    const float* __restrict__ scale_p,
    const float* __restrict__ Wo, const float* __restrict__ bo,
    const float* __restrict__ gamma, const float* __restrict__ beta,
    float* __restrict__ out,
    u16* __restrict__ qb, u16* __restrict__ kb, u16* __restrict__ vT,
    u16* __restrict__ xbuf, u16* __restrict__ WqkvT, u16* __restrict__ WoT,
    float* __restrict__ msgacc, float* __restrict__ lacc, int NZC)
{
    __shared__ SMem sm;
    cg::grid_group grid = cg::this_grid();
    const int G = gridDim.x;
    const int t = threadIdx.x;
    const int wave = t >> 6, lane = t & 63;
    const int l16 = lane & 15, quad = lane >> 4;

    // ---------------- Phase 0: zero accumulators + weight transpose + xconv
    {
        const size_t start = ((size_t)blockIdx.x * 256 + t) * 4;
        const size_t step = (size_t)G * 1024;
        const float4 zf = {0.f, 0.f, 0.f, 0.f};
        for (size_t i = start; i < ZERO_FLOATS; i += step)
            *(float4*)(msgacc + i) = zf;     // covers msgacc + lacc (contiguous)
    }
    for (int job = blockIdx.x; job < 512; job += G) {
        if (job < 256) {
            const int z = job >> 6;
            const int sub = job & 63;
            const int n0 = (sub & 7) * 32, k0 = (sub >> 3) * 32;
            const float* W = (z == 0) ? Wq : (z == 1) ? Wk : (z == 2) ? Wv : Wo;
            u16* WT = (z == 3) ? WoT : (WqkvT + (size_t)z * 65536);
            const int tx = t & 31, ty = t >> 5;
            __syncthreads();                 // protect tile reuse across jobs
            #pragma unroll
            for (int i = 0; i < 32; i += 8)
                sm.tile[ty + i][tx] = W[(size_t)(k0 + ty + i) * 256 + n0 + tx];
            __syncthreads();
            #pragma unroll
            for (int i = 0; i < 32; i += 8)
                WT[(size_t)(n0 + ty + i) * 256 + k0 + tx] = f2b(sm.tile[tx][ty + i]);
        } else {
            const int base = (job - 256) * 4096 + t * 16;
            #pragma unroll
            for (int i = 0; i < 4; ++i) {
                const float4 v = *(const float4*)(x + base + i * 4);
                union { u16 u[4]; unsigned long long ull; } pk;
                pk.u[0] = f2b(v.x); pk.u[1] = f2b(v.y);
                pk.u[2] = f2b(v.z); pk.u[3] = f2b(v.w);
                *(unsigned long long*)(xbuf + base + i * 4) = pk.ull;
            }
        }
    }
    grid.sync();

    // ---------------- Phase 1: QKV projection (64x64 MFMA tiles, 768 jobs)
    for (int job = blockIdx.x; job < 768; job += G) {
        const int m0 = (job & 63) * 64;
        const int n0 = (job >> 6) * 64;

        f32x4 acc[4];
        #pragma unroll
        for (int ct = 0; ct < 4; ++ct) acc[ct] = f32x4{0.f, 0.f, 0.f, 0.f};

        const u16* xrow = xbuf + (size_t)(m0 + wave * 16 + l16) * C;
        #pragma unroll
        for (int kk = 0; kk < 8; ++kk) {
            const bf16x8 af = *(const bf16x8*)(xrow + kk * 32 + quad * 8);
            #pragma unroll
            for (int ct = 0; ct < 4; ++ct) {
                const bf16x8 bfr = *(const bf16x8*)(
                    WqkvT + (size_t)(n0 + ct * 16 + l16) * C + kk * 32 + quad * 8);
                acc[ct] = __builtin_amdgcn_mfma_f32_16x16x32_bf16(af, bfr, acc[ct], 0, 0, 0);
            }
        }

        const int sect = n0 >> 8;             // block-uniform
        const int c0 = n0 & 255;
        const int rloc = wave * 16 + quad * 4;
        if (sect == 2) {
            #pragma unroll
            for (int ct = 0; ct < 4; ++ct) {
                const int c = c0 + ct * 16 + l16;
                const float b = bv[c];
                union { u16 u[4]; unsigned long long ull; } pk;
                #pragma unroll
                for (int r = 0; r < 4; ++r) pk.u[r] = f2b(acc[ct][r] + b);
                *(unsigned long long*)(vT + (size_t)c * NN + m0 + rloc) = pk.ull;
            }
        } else {
            const float scl = (sect == 0) ? (*scale_p) * LOG2E : 1.f;
            const float* bias = (sect == 0) ? bq : bk;
            __syncthreads();                  // protect tr reuse across jobs
            #pragma unroll
            for (int ct = 0; ct < 4; ++ct) {
                const float b = bias[c0 + ct * 16 + l16];
                #pragma unroll
                for (int r = 0; r < 4; ++r)
                    sm.tr[(rloc + r) * TRS + ct * 16 + l16] =
                        f2b((acc[ct][r] + b) * scl);
            }
            __syncthreads();
            const int row = t >> 2, chunk = t & 3;
            u16* dst = ((sect == 0) ? qb : kb)
                       + (size_t)(m0 + row) * C + c0 + chunk * 16;
            const u16* src = sm.tr + row * TRS + chunk * 16;
            *(bf16x8*)(dst)     = *(const bf16x8*)(src);
            *(bf16x8*)(dst + 8) = *(const bf16x8*)(src + 8);
        }
    }
    grid.sync();

    // ---------------- Phase 2: attention (512*NZC jobs, balanced key chunks)
    for (int job = blockIdx.x; job < 512 * NZC; job += G) {
        const int qbase = (job & 63) * TQ;
        const int h = (job >> 6) & 7;
        const int z = job >> 9;
        const int tile0 = (64 * z) / NZC, tile1 = (64 * (z + 1)) / NZC;

        const bf16x8 qfrag = *(const bf16x8*)(
            qb + (size_t)(qbase + wave * 16 + l16) * C + h * HD + quad * 8);

        float lsum = 0.f;
        f32x4 o0 = {0.f, 0.f, 0.f, 0.f};
        f32x4 o1 = {0.f, 0.f, 0.f, 0.f};

        const int sj = t >> 2, sc = t & 3;
        const int sd = t >> 3, se = t & 7;

        for (int j0 = tile0 * TJ; j0 < tile1 * TJ; j0 += TJ) {
            __syncthreads();
            *(bf16x8*)(sm.a.Ks + sj * KSTRIDE + sc * 8) =
                *(const bf16x8*)(kb + (size_t)(j0 + sj) * C + h * HD + sc * 8);
            *(bf16x8*)(sm.a.Vs + sd * VSTRIDE + se * 8) =
                *(const bf16x8*)(vT + (size_t)(h * HD + sd) * NN + j0 + se * 8);
            __syncthreads();

            f32x4 st[4];
            #pragma unroll
            for (int ct = 0; ct < 4; ++ct) {
                const bf16x8 kf = *(const bf16x8*)(
                    sm.a.Ks + (ct * 16 + l16) * KSTRIDE + quad * 8);
                f32x4 zz = {0.f, 0.f, 0.f, 0.f};
                st[ct] = __builtin_amdgcn_mfma_f32_16x16x32_bf16(kf, qfrag, zz, 0, 0, 0);
            }

            #pragma unroll
            for (int ct = 0; ct < 4; ++ct) {
                const float e0 = fexp2(st[ct][0]);
                const float e1 = fexp2(st[ct][1]);
                const float e2 = fexp2(st[ct][2]);
                const float e3 = fexp2(st[ct][3]);
                lsum += (e0 + e1) + (e2 + e3);
                const unsigned lo = pack_trunc(e0, e1);
                const unsigned hi = pack_trunc(e2, e3);
                *(unsigned long long*)(
                    &sm.a.Ps[wave][l16 * VSTRIDE + ct * 16 + quad * 4]) =
                    (unsigned long long)lo | ((unsigned long long)hi << 32);
            }

            asm volatile("s_waitcnt lgkmcnt(0)" ::: "memory");  // wave-private Ps

            #pragma unroll
            for (int ks = 0; ks < 2; ++ks) {
                const bf16x8 pf = *(const bf16x8*)(
                    &sm.a.Ps[wave][l16 * VSTRIDE + ks * 32 + quad * 8]);
                const bf16x8 vf0 = *(const bf16x8*)(
                    sm.a.Vs + l16 * VSTRIDE + ks * 32 + quad * 8);
                const bf16x8 vf1 = *(const bf16x8*)(
                    sm.a.Vs + (16 + l16) * VSTRIDE + ks * 32 + quad * 8);
                o0 = __builtin_amdgcn_mfma_f32_16x16x32_bf16(pf, vf0, o0, 0, 0, 0);
                o1 = __builtin_amdgcn_mfma_f32_16x16x32_bf16(pf, vf1, o1, 0, 0, 0);
            }
        }

        lsum += __shfl_xor(lsum, 16);
        lsum += __shfl_xor(lsum, 32);
        if (quad == 0)
            atomic_add_agent(&lacc[(size_t)(qbase + wave * 16 + l16) * NH + h], lsum);

        #pragma unroll
        for (int r = 0; r < 4; ++r) {
            const int row = qbase + wave * 16 + quad * 4 + r;
            atomic_add_agent(&msgacc[(size_t)row * C + h * HD + l16], o0[r]);
            atomic_add_agent(&msgacc[(size_t)row * C + h * HD + 16 + l16], o1[r]);
        }
    }
    grid.sync();

    // ---------------- Phase 3: out-proj + residual + LayerNorm (512 jobs)
    for (int job = blockIdx.x; job < NN / OROWS; job += G) {
        const int m0 = job * OROWS;
        const int w = wave;

        f32x4 acc[4];
        #pragma unroll
        for (int ct = 0; ct < 4; ++ct) acc[ct] = f32x4{0.f, 0.f, 0.f, 0.f};

        const int ar = min(m0 + l16, NN - 1);   // rows 8..15 -> discarded D rows
        const float* arow = msgacc + (size_t)ar * C;
        const float* lrow = lacc + (size_t)ar * NH;
        #pragma unroll
        for (int kk = 0; kk < 8; ++kk) {
            const float li = 1.f / lrow[kk];
            const float4 a0 = *(const float4*)(arow + kk * 32 + quad * 8);
            const float4 a1 = *(const float4*)(arow + kk * 32 + quad * 8 + 4);
            union { unsigned u[4]; bf16x8 v; } af;
            af.u[0] = pack_trunc(a0.x * li, a0.y * li);
            af.u[1] = pack_trunc(a0.z * li, a0.w * li);
            af.u[2] = pack_trunc(a1.x * li, a1.y * li);
            af.u[3] = pack_trunc(a1.z * li, a1.w * li);
            #pragma unroll
            for (int ct = 0; ct < 4; ++ct) {
                const bf16x8 bfr = *(const bf16x8*)(
                    WoT + (size_t)(w * 64 + ct * 16 + l16) * C + kk * 32 + quad * 8);
                acc[ct] = __builtin_amdgcn_mfma_f32_16x16x32_bf16(af.v, bfr, acc[ct], 0, 0, 0);
            }
        }

        __syncthreads();                       // protect sums reuse across jobs
        float val[4][4];
        if (quad < 2) {
            #pragma unroll
            for (int r = 0; r < 4; ++r) {
                const int row = m0 + quad * 4 + r;
                float sr = 0.f, qr = 0.f;
                #pragma unroll
                for (int ct = 0; ct < 4; ++ct) {
                    const int c = w * 64 + ct * 16 + l16;
                    const float v = acc[ct][r] + bo[c] + x[(size_t)row * C + c];
                    val[ct][r] = v;
                    sr += v;
                    qr = fmaf(v, v, qr);
                }
                sr += __shfl_xor(sr, 1); sr += __shfl_xor(sr, 2);
                sr += __shfl_xor(sr, 4); sr += __shfl_xor(sr, 8);
                qr += __shfl_xor(qr, 1); qr += __shfl_xor(qr, 2);
                qr += __shfl_xor(qr, 4); qr += __shfl_xor(qr, 8);
                if (l16 == 0) {
                    sm.sums[0][w][quad * 4 + r] = sr;
                    sm.sums[1][w][quad * 4 + r] = qr;
                }
            }
        }
        __syncthreads();

        if (quad < 2) {
            #pragma unroll
            for (int r = 0; r < 4; ++r) {
                const int ri = quad * 4 + r;
                const int row = m0 + ri;
                const float tot  = sm.sums[0][0][ri] + sm.sums[0][1][ri]
                                 + sm.sums[0][2][ri] + sm.sums[0][3][ri];
                const float tot2 = sm.sums[1][0][ri] + sm.sums[1][1][ri]
                                 + sm.sums[1][2][ri] + sm.sums[1][3][ri];
                const float mu = tot * (1.f / C);
                const float var = fmaxf(tot2 * (1.f / C) - mu * mu, 0.f);
                const float rstd = rsqrtf(var + LN_EPS);
                #pragma unroll
                for (int ct = 0; ct < 4; ++ct) {
                    const int c = w * 64 + ct * 16 + l16;
                    out[(size_t)row * C + c] =
                        (val[ct][r] - mu) * rstd * gamma[c] + beta[c];
                }
            }
        }
    }
}

// ---------------------------------------------------------------------------
extern "C" void kernel_launch(void* const* d_in, const int* in_sizes, int n_in,
                              void* d_out, int out_size, void* d_ws, size_t ws_size,
                              hipStream_t stream) {
    const float* x     = (const float*)d_in[0];
    const float* Wq    = (const float*)d_in[1];
    const float* bq    = (const float*)d_in[2];
    const float* Wk    = (const float*)d_in[3];
    const float* bk    = (const float*)d_in[4];
    const float* Wv    = (const float*)d_in[5];
    const float* bv    = (const float*)d_in[6];
    const float* scale = (const float*)d_in[7];
    const float* Wo    = (const float*)d_in[8];
    const float* bo    = (const float*)d_in[9];
    const float* gamma = (const float*)d_in[10];
    const float* beta  = (const float*)d_in[11];
    float* out = (float*)d_out;

    u16* qb     = (u16*)d_ws;                              // 2 MB
    u16* kb     = qb + (size_t)NN * C;                     // 2 MB
    u16* vT     = kb + (size_t)NN * C;                     // 2 MB
    u16* xbuf   = vT + (size_t)NN * C;                     // 2 MB
    u16* WqkvT  = xbuf + (size_t)NN * C;                   // 384 KB
    u16* WoT    = WqkvT + (size_t)3 * C * C;               // 128 KB
    float* msgacc = (float*)(WoT + (size_t)C * C);         // 4 MB
    float* lacc   = msgacc + (size_t)NN * C;               // 128 KB (contiguous)

    // co-residency-safe cooperative grid (multiple of 512 for attn balance)
    int maxB = 0;
    hipOccupancyMaxActiveBlocksPerMultiprocessor(&maxB, fused_kernel, 256, 0);
    if (maxB < 1) maxB = 1;
    int G = maxB * 256;
    if (G > 2048) G = 2048;
    if (G >= 512) G = (G / 512) * 512;
    int NZC = (G >= 512) ? (G / 512) : 1;

    void* args[] = {
        (void*)&x, (void*)&Wq, (void*)&bq, (void*)&Wk, (void*)&bk,
        (void*)&Wv, (void*)&bv, (void*)&scale, (void*)&Wo, (void*)&bo,
        (void*)&gamma, (void*)&beta, (void*)&out,
        (void*)&qb, (void*)&kb, (void*)&vT, (void*)&xbuf,
        (void*)&WqkvT, (void*)&WoT, (void*)&msgacc, (void*)&lacc, (void*)&NZC,
    };
    hipLaunchCooperativeKernel(fused_kernel, dim3(G), dim3(256), args, 0, stream);
}

// Round 11
// 162.157 us; speedup vs baseline: 2.6229x; 2.6229x over previous
//
#include <hip/hip_runtime.h>
#include <hip/hip_bf16.h>
#include <math.h>

#define NN 4096      // nodes
#define C  256       // feature dim
#define NH 8         // heads
#define HD 32        // head dim
#define LN_EPS 1e-5f
#define LOG2E 1.44269504088896340736f

typedef unsigned short u16;
typedef __attribute__((ext_vector_type(8))) short bf16x8;
typedef __attribute__((ext_vector_type(4))) float f32x4;

__device__ inline u16 f2b(float f) {
    union { float f; unsigned u; } v; v.f = f;
    unsigned r = (v.u + 0x7fff + ((v.u >> 16) & 1)) >> 16;  // RNE
    return (u16)r;
}

__device__ inline float fexp2(float x) {
#if __has_builtin(__builtin_amdgcn_exp2f)
    return __builtin_amdgcn_exp2f(x);      // single v_exp_f32
#else
    return exp2f(x);
#endif
}

// pack bf16(e0) | bf16(e1)<<16 by truncation: ONE v_perm_b32
__device__ inline unsigned pack_trunc(float e0, float e1) {
    return __builtin_amdgcn_perm(__float_as_uint(e1), __float_as_uint(e0),
                                 0x07060302u);
}

// ---------------------------------------------------------------------------
// Kernel 0: prep — z<4: weight transpose+bf16 (WqkvT=[Wq^T|Wk^T|Wv^T], WoT);
// z=4..7: x fp32->bf16. grid (8,8,8), block 256.
// ---------------------------------------------------------------------------
__global__ __launch_bounds__(256) void prep_kernel(
    const float* __restrict__ Wq, const float* __restrict__ Wk,
    const float* __restrict__ Wv, const float* __restrict__ Wo,
    const float* __restrict__ x,
    u16* __restrict__ WqkvT, u16* __restrict__ WoT, u16* __restrict__ xb)
{
    const int z = blockIdx.z;
    if (z < 4) {
        __shared__ float tile[32][33];
        const float* W = (z == 0) ? Wq : (z == 1) ? Wk : (z == 2) ? Wv : Wo;
        u16* WT = (z == 3) ? WoT : (WqkvT + (size_t)z * 256 * 256);
        const int tx = threadIdx.x & 31, ty = threadIdx.x >> 5;
        const int n0 = blockIdx.x * 32, k0 = blockIdx.y * 32;
        #pragma unroll
        for (int i = 0; i < 32; i += 8)
            tile[ty + i][tx] = W[(size_t)(k0 + ty + i) * 256 + n0 + tx];
        __syncthreads();
        #pragma unroll
        for (int i = 0; i < 32; i += 8)
            WT[(size_t)(n0 + ty + i) * 256 + k0 + tx] = f2b(tile[tx][ty + i]);
    } else {
        const int slice = z - 4;
        const int bid = blockIdx.x * 8 + blockIdx.y;
        const int base = slice * (NN * C / 4) + bid * 4096 + threadIdx.x * 16;
        #pragma unroll
        for (int i = 0; i < 4; ++i) {
            const float4 v = *(const float4*)(x + base + i * 4);
            union { u16 u[4]; unsigned long long ull; } pk;
            pk.u[0] = f2b(v.x); pk.u[1] = f2b(v.y);
            pk.u[2] = f2b(v.z); pk.u[3] = f2b(v.w);
            *(unsigned long long*)(xb + base + i * 4) = pk.ull;
        }
    }
}

// ---------------------------------------------------------------------------
// Kernel 1: QKV projection via MFMA (64x64 tiles, 4 waves). q/k epilogue via
// LDS transpose -> coalesced b128 stores; v as packed V^T column stores.
// ---------------------------------------------------------------------------
#define TRS 80   // LDS transpose row stride in u16 (160B: 16B-aligned rows)
__global__ __launch_bounds__(256) void qkv_mfma_kernel(
    const u16* __restrict__ xb, const u16* __restrict__ WT,
    const float* __restrict__ bq, const float* __restrict__ bk,
    const float* __restrict__ bv, const float* __restrict__ scale_p,
    u16* __restrict__ qb, u16* __restrict__ kb, u16* __restrict__ vT)
{
    __shared__ u16 tr[64 * TRS];
    const int m0 = blockIdx.x * 64;
    const int n0 = blockIdx.y * 64;
    const int t = threadIdx.x;
    const int wave = t >> 6, lane = t & 63;
    const int l16 = lane & 15, quad = lane >> 4;

    f32x4 acc[4];
    #pragma unroll
    for (int ct = 0; ct < 4; ++ct) acc[ct] = f32x4{0.f, 0.f, 0.f, 0.f};

    const u16* xrow = xb + (size_t)(m0 + wave * 16 + l16) * C;
    #pragma unroll
    for (int kk = 0; kk < 8; ++kk) {
        const bf16x8 af = *(const bf16x8*)(xrow + kk * 32 + quad * 8);
        #pragma unroll
        for (int ct = 0; ct < 4; ++ct) {
            const bf16x8 bfr = *(const bf16x8*)(
                WT + (size_t)(n0 + ct * 16 + l16) * C + kk * 32 + quad * 8);
            acc[ct] = __builtin_amdgcn_mfma_f32_16x16x32_bf16(af, bfr, acc[ct], 0, 0, 0);
        }
    }

    const int sect = n0 >> 8;                // block-uniform
    const int c0 = n0 & 255;
    const int rloc = wave * 16 + quad * 4;   // local row base in the 64-tile
    if (sect == 2) {
        #pragma unroll
        for (int ct = 0; ct < 4; ++ct) {
            const int c = c0 + ct * 16 + l16;
            const float b = bv[c];
            union { u16 u[4]; unsigned long long ull; } pk;
            #pragma unroll
            for (int r = 0; r < 4; ++r) pk.u[r] = f2b(acc[ct][r] + b);
            *(unsigned long long*)(vT + (size_t)c * NN + m0 + rloc) = pk.ull;
        }
    } else {
        const float scl = (sect == 0) ? (*scale_p) * LOG2E : 1.f;
        const float* bias = (sect == 0) ? bq : bk;
        #pragma unroll
        for (int ct = 0; ct < 4; ++ct) {
            const float b = bias[c0 + ct * 16 + l16];
            #pragma unroll
            for (int r = 0; r < 4; ++r)
                tr[(rloc + r) * TRS + ct * 16 + l16] = f2b((acc[ct][r] + b) * scl);
        }
        __syncthreads();
        const int row = t >> 2, chunk = t & 3;
        u16* dst = ((sect == 0) ? qb : kb)
                   + (size_t)(m0 + row) * C + c0 + chunk * 16;
        const u16* src = tr + row * TRS + chunk * 16;
        *(bf16x8*)(dst)     = *(const bf16x8*)(src);
        *(bf16x8*)(dst + 8) = *(const bf16x8*)(src + 8);
    }
}

// ---------------------------------------------------------------------------
// Kernel 2: MFMA attention, S^T formulation, no max-shift, key-split NZ=4.
// Epilogue: PLAIN stores into per-z partial buffers (each slot written exactly
// once -> no zero-init, no memset node, no atomic L2 round-trips).
// ---------------------------------------------------------------------------
#define TQ 64
#define TJ 64
#define NZ 4
#define ZT (NN / NZ)
#define KSTRIDE 40
#define VSTRIDE 72

__global__ __launch_bounds__(256) void attn_mfma_kernel(
    const u16* __restrict__ q, const u16* __restrict__ k,
    const u16* __restrict__ vT, float* __restrict__ msgp,
    float* __restrict__ lp)
{
    __shared__ u16 Ks[TJ * KSTRIDE];
    __shared__ u16 Vs[HD * VSTRIDE];
    __shared__ u16 Ps[4][16 * VSTRIDE];

    const int qbase = blockIdx.x * TQ;
    const int h = blockIdx.y;
    const int z = blockIdx.z;
    const int t = threadIdx.x;
    const int wave = t >> 6;
    const int lane = t & 63;
    const int l16 = lane & 15;
    const int quad = lane >> 4;

    const bf16x8 qfrag = *(const bf16x8*)(
        q + (size_t)(qbase + wave * 16 + l16) * C + h * HD + quad * 8);

    float lsum = 0.f;
    f32x4 o0 = {0.f, 0.f, 0.f, 0.f};
    f32x4 o1 = {0.f, 0.f, 0.f, 0.f};

    const int sj = t >> 2, sc = t & 3;
    const int sd = t >> 3, se = t & 7;

    for (int j0 = z * ZT; j0 < z * ZT + ZT; j0 += TJ) {
        __syncthreads();
        *(bf16x8*)(Ks + sj * KSTRIDE + sc * 8) =
            *(const bf16x8*)(k + (size_t)(j0 + sj) * C + h * HD + sc * 8);
        *(bf16x8*)(Vs + sd * VSTRIDE + se * 8) =
            *(const bf16x8*)(vT + (size_t)(h * HD + sd) * NN + j0 + se * 8);
        __syncthreads();

        f32x4 st[4];
        #pragma unroll
        for (int ct = 0; ct < 4; ++ct) {
            const bf16x8 kf = *(const bf16x8*)(Ks + (ct * 16 + l16) * KSTRIDE + quad * 8);
            f32x4 zz = {0.f, 0.f, 0.f, 0.f};
            st[ct] = __builtin_amdgcn_mfma_f32_16x16x32_bf16(kf, qfrag, zz, 0, 0, 0);
        }

        #pragma unroll
        for (int ct = 0; ct < 4; ++ct) {
            const float e0 = fexp2(st[ct][0]);
            const float e1 = fexp2(st[ct][1]);
            const float e2 = fexp2(st[ct][2]);
            const float e3 = fexp2(st[ct][3]);
            lsum += (e0 + e1) + (e2 + e3);
            const unsigned lo = pack_trunc(e0, e1);
            const unsigned hi = pack_trunc(e2, e3);
            *(unsigned long long*)(&Ps[wave][l16 * VSTRIDE + ct * 16 + quad * 4]) =
                (unsigned long long)lo | ((unsigned long long)hi << 32);
        }

        asm volatile("s_waitcnt lgkmcnt(0)" ::: "memory");  // wave-private Ps

        #pragma unroll
        for (int ks = 0; ks < 2; ++ks) {
            const bf16x8 pf = *(const bf16x8*)(&Ps[wave][l16 * VSTRIDE + ks * 32 + quad * 8]);
            const bf16x8 vf0 = *(const bf16x8*)(Vs + l16 * VSTRIDE + ks * 32 + quad * 8);
            const bf16x8 vf1 = *(const bf16x8*)(Vs + (16 + l16) * VSTRIDE + ks * 32 + quad * 8);
            o0 = __builtin_amdgcn_mfma_f32_16x16x32_bf16(pf, vf0, o0, 0, 0, 0);
            o1 = __builtin_amdgcn_mfma_f32_16x16x32_bf16(pf, vf1, o1, 0, 0, 0);
        }
    }

    lsum += __shfl_xor(lsum, 16);
    lsum += __shfl_xor(lsum, 32);
    if (quad == 0)
        lp[(size_t)z * NN * NH + (size_t)(qbase + wave * 16 + l16) * NH + h] = lsum;

    float* mz = msgp + (size_t)z * NN * C;
    #pragma unroll
    for (int r = 0; r < 4; ++r) {
        const int row = qbase + wave * 16 + quad * 4 + r;
        mz[(size_t)row * C + h * HD + l16]      = o0[r];
        mz[(size_t)row * C + h * HD + 16 + l16] = o1[r];
    }
}

// ---------------------------------------------------------------------------
// Kernel 3: y = x + (Σz msgp / Σz lp) @ Wo + bo, LayerNorm. 8-row tiles,
// 512 blocks. A-build sums the 4 partials and packs via v_perm truncation.
// ---------------------------------------------------------------------------
#define OROWS 8
__global__ __launch_bounds__(256) void out_ln_mfma_kernel(
    const float* __restrict__ msgp, const float* __restrict__ lp,
    const u16* __restrict__ WoT, const float* __restrict__ bo,
    const float* __restrict__ x, const float* __restrict__ gamma,
    const float* __restrict__ beta, float* __restrict__ out)
{
    __shared__ float sums[2][4][OROWS];
    const int m0 = blockIdx.x * OROWS;
    const int t = threadIdx.x;
    const int w = t >> 6, lane = t & 63;
    const int l16 = lane & 15, quad = lane >> 4;

    f32x4 acc[4];
    #pragma unroll
    for (int ct = 0; ct < 4; ++ct) acc[ct] = f32x4{0.f, 0.f, 0.f, 0.f};

    const int ar = min(m0 + l16, NN - 1);    // rows 8..15 feed discarded D rows
    const float* arow = msgp + (size_t)ar * C;
    const float* lrow = lp + (size_t)ar * NH;
    #pragma unroll
    for (int kk = 0; kk < 8; ++kk) {
        const float lt = (lrow[kk] + lrow[(size_t)NN * NH + kk])
                       + (lrow[(size_t)2 * NN * NH + kk] + lrow[(size_t)3 * NN * NH + kk]);
        const float li = 1.f / lt;
        float4 a0 = *(const float4*)(arow + kk * 32 + quad * 8);
        float4 a1 = *(const float4*)(arow + kk * 32 + quad * 8 + 4);
        #pragma unroll
        for (int z = 1; z < NZ; ++z) {
            const float4 b0 = *(const float4*)(arow + (size_t)z * NN * C + kk * 32 + quad * 8);
            const float4 b1 = *(const float4*)(arow + (size_t)z * NN * C + kk * 32 + quad * 8 + 4);
            a0.x += b0.x; a0.y += b0.y; a0.z += b0.z; a0.w += b0.w;
            a1.x += b1.x; a1.y += b1.y; a1.z += b1.z; a1.w += b1.w;
        }
        union { unsigned u[4]; bf16x8 v; } af;
        af.u[0] = pack_trunc(a0.x * li, a0.y * li);
        af.u[1] = pack_trunc(a0.z * li, a0.w * li);
        af.u[2] = pack_trunc(a1.x * li, a1.y * li);
        af.u[3] = pack_trunc(a1.z * li, a1.w * li);
        #pragma unroll
        for (int ct = 0; ct < 4; ++ct) {
            const bf16x8 bfr = *(const bf16x8*)(
                WoT + (size_t)(w * 64 + ct * 16 + l16) * C + kk * 32 + quad * 8);
            acc[ct] = __builtin_amdgcn_mfma_f32_16x16x32_bf16(af.v, bfr, acc[ct], 0, 0, 0);
        }
    }

    float val[4][4];
    if (quad < 2) {
        #pragma unroll
        for (int r = 0; r < 4; ++r) {
            const int row = m0 + quad * 4 + r;
            float sr = 0.f, qr = 0.f;
            #pragma unroll
            for (int ct = 0; ct < 4; ++ct) {
                const int c = w * 64 + ct * 16 + l16;
                const float v = acc[ct][r] + bo[c] + x[(size_t)row * C + c];
                val[ct][r] = v;
                sr += v;
                qr = fmaf(v, v, qr);
            }
            sr += __shfl_xor(sr, 1); sr += __shfl_xor(sr, 2);
            sr += __shfl_xor(sr, 4); sr += __shfl_xor(sr, 8);
            qr += __shfl_xor(qr, 1); qr += __shfl_xor(qr, 2);
            qr += __shfl_xor(qr, 4); qr += __shfl_xor(qr, 8);
            if (l16 == 0) {
                sums[0][w][quad * 4 + r] = sr;
                sums[1][w][quad * 4 + r] = qr;
            }
        }
    }
    __syncthreads();

    if (quad < 2) {
        #pragma unroll
        for (int r = 0; r < 4; ++r) {
            const int ri = quad * 4 + r;
            const int row = m0 + ri;
            const float tot  = sums[0][0][ri] + sums[0][1][ri] + sums[0][2][ri] + sums[0][3][ri];
            const float tot2 = sums[1][0][ri] + sums[1][1][ri] + sums[1][2][ri] + sums[1][3][ri];
            const float mu = tot * (1.f / C);
            const float var = fmaxf(tot2 * (1.f / C) - mu * mu, 0.f);
            const float rstd = rsqrtf(var + LN_EPS);
            #pragma unroll
            for (int ct = 0; ct < 4; ++ct) {
                const int c = w * 64 + ct * 16 + l16;
                out[(size_t)row * C + c] = (val[ct][r] - mu) * rstd * gamma[c] + beta[c];
            }
        }
    }
}

// ---------------------------------------------------------------------------
extern "C" void kernel_launch(void* const* d_in, const int* in_sizes, int n_in,
                              void* d_out, int out_size, void* d_ws, size_t ws_size,
                              hipStream_t stream) {
    const float* x     = (const float*)d_in[0];
    const float* Wq    = (const float*)d_in[1];
    const float* bq    = (const float*)d_in[2];
    const float* Wk    = (const float*)d_in[3];
    const float* bk    = (const float*)d_in[4];
    const float* Wv    = (const float*)d_in[5];
    const float* bv    = (const float*)d_in[6];
    const float* scale = (const float*)d_in[7];
    const float* Wo    = (const float*)d_in[8];
    const float* bo    = (const float*)d_in[9];
    const float* gamma = (const float*)d_in[10];
    const float* beta  = (const float*)d_in[11];
    float* out = (float*)d_out;

    u16* qb     = (u16*)d_ws;                              // 2 MB
    u16* kb     = qb + (size_t)NN * C;                     // 2 MB
    u16* vT     = kb + (size_t)NN * C;                     // 2 MB
    u16* xbuf   = vT + (size_t)NN * C;                     // 2 MB
    u16* WqkvT  = xbuf + (size_t)NN * C;                   // 384 KB
    u16* WoT    = WqkvT + (size_t)3 * C * C;               // 128 KB
    float* msgp = (float*)(WoT + (size_t)C * C);           // NZ * 4 MB
    float* lp   = msgp + (size_t)NZ * NN * C;              // NZ * 128 KB

    prep_kernel<<<dim3(8, 8, 8), 256, 0, stream>>>(Wq, Wk, Wv, Wo, x,
                                                   WqkvT, WoT, xbuf);
    qkv_mfma_kernel<<<dim3(NN / 64, 12), 256, 0, stream>>>(
        xbuf, WqkvT, bq, bk, bv, scale, qb, kb, vT);
    attn_mfma_kernel<<<dim3(NN / TQ, NH, NZ), 256, 0, stream>>>(
        qb, kb, vT, msgp, lp);
    out_ln_mfma_kernel<<<NN / OROWS, 256, 0, stream>>>(msgp, lp, WoT, bo, x,
                                                       gamma, beta, out);
}